// Round 3
// baseline (31.139 us; speedup 1.0000x reference)
//
#include <hip/hip_runtime.h>
#include <math.h>

// CMaxPool4d v3: input (8, 2, 32, 16, 16, 16, 16) fp32.
// r = in[:,0], i = in[:,1]; mod = sqrt_rn(r*r+i*i); 2x2x2x2 window argmax over
// mod (first-occurrence wins, np.argmax) -> emit (r,i) at argmax.
// Output (8, 2, 32, 8, 8, 8, 8).
//
// v3: back to v1's thread-local 2-windows-per-thread layout (v2's wave-
// contiguous loads were perf-identical), but the hot-path comparison is on the
// SQUARED modulus s = r*r + i*i (contract-off, bit-matching numpy's
// intermediate). sqrt is monotone, so s-comparison matches mod-comparison
// EXCEPT when two s values round to the same fp32 sqrt: that needs
// relative gap <= ~2.4e-7 (sqrt compresses 2 ulps -> 1). We detect
// gap <= 4e-7 (conservative) and only then consult exact __fsqrt_rn of both
// (probability ~4e-7 per comparison -> the branch is execz-skipped in
// virtually every wave). Tie semantics match np.argmax exactly:
//  - s_new <= s_old            -> keep old (sqrt monotone: m_new <= m_old)
//  - s_new >  s_old, gap large -> take new (sqrts provably differ)
//  - s_new >  s_old, gap tiny  -> take new iff sqrt_rn(new) > sqrt_rn(old)

__device__ __forceinline__ void upd_cand(float r, float i, float s,
                                         float& bs, float& br, float& bi)
{
    const float diff = s - bs;
    bool gt = diff > 0.0f;
    const bool near_tie = gt & (diff <= bs * 4.0e-7f);  // bs=-1 sentinel: false
    if (__builtin_expect(near_tie, 0)) {
        gt = __fsqrt_rn(s) > __fsqrt_rn(bs);            // rare exact resolve
    }
    if (gt) { bs = s; br = r; bi = i; }
}

__global__ __launch_bounds__(256) void cmaxpool4d_v3(
    const float* __restrict__ in, float* __restrict__ out)
{
#pragma clang fp contract(off)   // bit-match numpy: no FMA fusion of r*r + i*i
    const int t = blockIdx.x * 256 + threadIdx.x;

    const int t4 = t & 3;          // o4 = 2*t4, 2*t4+1  (d4 base = 4*t4)
    const int o3 = (t >> 2) & 7;
    const int o2 = (t >> 5) & 7;
    const int o1 = (t >> 8) & 7;
    const int c  = (t >> 11) & 31;
    const int b  = t >> 16;

    const size_t planeElems = 65536;                 // 16^4
    const float* __restrict__ pr = in + (((size_t)b * 2 + 0) * 32 + c) * planeElems;
    const float* __restrict__ pi = in + (((size_t)b * 2 + 1) * 32 + c) * planeElems;

    float bs0 = -1.0f, br0 = 0.0f, bi0 = 0.0f;   // window 0 (o4 = 2*t4)
    float bs1 = -1.0f, br1 = 0.0f, bi1 = 0.0f;   // window 1 (o4 = 2*t4+1)

    const int d4b = 4 * t4;

    // scan order: w = k1*8 + k2*4 + k3*2 + k4 strictly ascending -> the
    // update rule's strict-ness gives np.argmax first-occurrence semantics.
#pragma unroll
    for (int k1 = 0; k1 < 2; ++k1) {
        const int d1 = 2 * o1 + k1;
#pragma unroll
        for (int k2 = 0; k2 < 2; ++k2) {
            const int d2 = 2 * o2 + k2;
#pragma unroll
            for (int k3 = 0; k3 < 2; ++k3) {
                const int d3 = 2 * o3 + k3;
                const size_t off = (((size_t)d1 * 16 + d2) * 16 + d3) * 16 + d4b;
                const float4 r4 = *reinterpret_cast<const float4*>(pr + off);
                const float4 i4 = *reinterpret_cast<const float4*>(pi + off);

                float rr, ii, s;
                // k4 = 0 (x), k4 = 1 (y) -> window 0
                rr = r4.x * r4.x; ii = i4.x * i4.x; s = rr + ii;
                upd_cand(r4.x, i4.x, s, bs0, br0, bi0);
                rr = r4.y * r4.y; ii = i4.y * i4.y; s = rr + ii;
                upd_cand(r4.y, i4.y, s, bs0, br0, bi0);
                // z, w -> window 1
                rr = r4.z * r4.z; ii = i4.z * i4.z; s = rr + ii;
                upd_cand(r4.z, i4.z, s, bs1, br1, bi1);
                rr = r4.w * r4.w; ii = i4.w * i4.w; s = rr + ii;
                upd_cand(r4.w, i4.w, s, bs1, br1, bi1);
            }
        }
    }

    // output: (((b*2+ch)*32 + c)*4096) + o1*512 + o2*64 + o3*8 + o4
    const size_t outPlane = 4096;                     // 8^4
    const size_t oOff = (size_t)o1 * 512 + (size_t)o2 * 64 + (size_t)o3 * 8 + 2 * t4;
    float* __restrict__ qr = out + (((size_t)b * 2 + 0) * 32 + c) * outPlane + oOff;
    float* __restrict__ qi = out + (((size_t)b * 2 + 1) * 32 + c) * outPlane + oOff;

    *reinterpret_cast<float2*>(qr) = make_float2(br0, br1);
    *reinterpret_cast<float2*>(qi) = make_float2(bi0, bi1);
}

extern "C" void kernel_launch(void* const* d_in, const int* in_sizes, int n_in,
                              void* d_out, int out_size, void* d_ws, size_t ws_size,
                              hipStream_t stream) {
    (void)in_sizes; (void)n_in; (void)d_ws; (void)ws_size; (void)out_size;
    const float* in = (const float*)d_in[0];
    float* out = (float*)d_out;

    const int nThreads = 8 * 32 * 8 * 8 * 8 * 4;     // 524288
    const int block = 256;
    const int grid = nThreads / block;               // 2048
    cmaxpool4d_v3<<<grid, block, 0, stream>>>(in, out);
}